// Round 6
// baseline (1077.527 us; speedup 1.0000x reference)
//
#include <hip/hip_runtime.h>

#define C_CH 16
#define Hdim 128
#define Wdim 128
#define HWdim 16384
#define CHW (C_CH * HWdim)                 // 262144 floats: one [C][H][W] slab
#define Bdim 2
#define PAIR_ELEMS (Bdim * CHW)            // 524288

// padded canvas geometry (border 3 = max P/2, zeroed once per launch)
#define HP 134
#define WP 136
#define PL (HP * WP)                       // 18224 floats per plane

__device__ __forceinline__ void gadd(float* p, float v) {
  __hip_atomic_fetch_add(p, v, __ATOMIC_RELAXED, __HIP_MEMORY_SCOPE_AGENT);
}

// ---------------------------------------------------------------------------
// Prep: memT[d][m] = mem * temp/sqrt(D)   (sim conv weights, m-contiguous)
//       memR[m][u][v][c]                  (kernel-flipped, c-contiguous)
// ---------------------------------------------------------------------------
struct PrepDesc {
  const float* mem;
  const float* temp;
  float* memT;
  float* memR;
  int M, D, P;
};
struct PrepArgs { PrepDesc d[6]; };

__global__ __launch_bounds__(256) void k_prep(PrepArgs a) {
  PrepDesc de = a.d[blockIdx.y];
  int n = de.M * de.D;
  int idx = blockIdx.x * 256 + threadIdx.x;
  if (idx >= n) return;
  int m = idx / de.D;
  int d = idx - m * de.D;
  float v = de.mem[idx];
  float sc = de.temp[0] / sqrtf((float)de.D);
  de.memT[d * de.M + m] = v * sc;
  int pp = de.P * de.P;
  int c = d / pp;
  int r = d - c * pp;
  int i = r / de.P;
  int j = r - i * de.P;
  de.memR[((m * de.P + (de.P - 1 - i)) * de.P + (de.P - 1 - j)) * C_CH + c] = v;
}

// ---------------------------------------------------------------------------
// Copy inputs into padded canvas: xpad plane order [bg b0, bg b1, tg b0, tg b1]
// ---------------------------------------------------------------------------
__global__ __launch_bounds__(256) void k_padx(const float* __restrict__ bg,
                                              const float* __restrict__ tg,
                                              float* __restrict__ xpad)
{
  int idx = blockIdx.x * 256 + threadIdx.x;     // 64 planes * HW
  int p = idx >> 14;                            // plane 0..63
  int hw = idx & (HWdim - 1);
  int y = hw >> 7, x = hw & 127;
  int z = p >> 4, c = p & 15;
  const float* src = (z < 2) ? bg : tg;
  int b = z & 1;
  float v = src[((b * C_CH + c) << 14) + hw];
  xpad[(size_t)p * PL + (y + 3) * WP + (x + 3)] = v;
}

// ---------------------------------------------------------------------------
// Sim conv + per-pixel softmax -> att (padded layout). One dispatch per scale.
// 8x8 tile, 512 thr, 8 waves split M. z: {bg b0, bg b1, tg b0, tg b1}.
// ---------------------------------------------------------------------------
template<int P, int M, int MC>
__device__ __forceinline__ void sim_core(
    const float* __restrict__ xt, float* __restrict__ red,
    const float* __restrict__ memT, float* __restrict__ att,
    int wv, int lane, int x0, int y0)
{
  constexpr int TH = 8 + P - 1, SR = TH + 1;
  const int px = lane & 7, py = lane >> 3;
  const int m0 = wv * MC;
  float acc[MC];
#pragma unroll
  for (int mm = 0; mm < MC; ++mm) acc[mm] = 0.f;

  for (int c = 0; c < C_CH; ++c) {
#pragma unroll
    for (int i = 0; i < P; ++i) {
#pragma unroll
      for (int j = 0; j < P; ++j) {
        float val = xt[(c * TH + py + i) * SR + (px + j)];
        const float* wr = memT + (size_t)(((c * P + i) * P + j)) * M + m0;
#pragma unroll
        for (int mm = 0; mm < MC; ++mm) acc[mm] = fmaf(val, wr[mm], acc[mm]);
      }
    }
  }

  float pm = acc[0];
#pragma unroll
  for (int mm = 1; mm < MC; ++mm) pm = fmaxf(pm, acc[mm]);
  red[wv * 64 + lane] = pm;
  __syncthreads();
  float gm = red[lane];
#pragma unroll
  for (int w = 1; w < 8; ++w) gm = fmaxf(gm, red[w * 64 + lane]);
  __syncthreads();
  float ps = 0.f;
#pragma unroll
  for (int mm = 0; mm < MC; ++mm) { acc[mm] = __expf(acc[mm] - gm); ps += acc[mm]; }
  red[wv * 64 + lane] = ps;
  __syncthreads();
  float tot = 0.f;
#pragma unroll
  for (int w = 0; w < 8; ++w) tot += red[w * 64 + lane];
  float inv = 1.f / tot;

  const int gy = y0 + py, gx = x0 + px;
#pragma unroll
  for (int mm = 0; mm < MC; ++mm)
    att[(size_t)(m0 + mm) * PL + (gy + 3) * WP + (gx + 3)] = acc[mm] * inv;
}

template<int P>
__global__ __launch_bounds__(512, 8) void k_sim(
    const float* __restrict__ xpad,
    const float* __restrict__ memTbg, const float* __restrict__ memTtg,
    float* __restrict__ attbg,   // [2][64] padded planes
    float* __restrict__ atttg)   // [2][8]  padded planes
{
  constexpr int PAD = P / 2, TH = 8 + P - 1, SR = TH + 1;
  __shared__ float xt[C_CH * TH * SR];
  __shared__ float red[8 * 64];

  const int tid = threadIdx.x;
  const int wv = __builtin_amdgcn_readfirstlane(tid >> 6);
  const int lane = tid & 63;
  const int x0 = blockIdx.x * 8, y0 = blockIdx.y * 8;
  const int z = blockIdx.z;
  const bool isbg = z < 2;
  const int b = z & 1;

  const float* xp = xpad + (size_t)(z * 16) * PL;
  const int oy = y0 + 3 - PAD, ox = x0 + 3 - PAD;
  for (int t = tid; t < C_CH * TH * TH; t += 512) {
    int c = t / (TH * TH);
    int r = t - c * (TH * TH);
    int ly = r / TH, lx = r - ly * TH;
    xt[(c * TH + ly) * SR + lx] = xp[(size_t)c * PL + (oy + ly) * WP + ox + lx];
  }
  __syncthreads();

  if (isbg) sim_core<P, 64, 8>(xt, red, memTbg, attbg + (size_t)(b * 64) * PL, wv, lane, x0, y0);
  else      sim_core<P, 8, 1>(xt, red, memTtg, atttg + (size_t)(b * 8) * PL, wv, lane, x0, y0);
}

// ---------------------------------------------------------------------------
// Read conv: 8x8 tile, 256 thr = 64 px x 4 c-quads (quad == wave). Streams ALL
// M planes through an 8-plane LDS chunk loop (bg 8 chunks, tg 1) -> each thread
// writes its 4 FINAL channel values (no partial slabs). Tile channel-sums are
// wave-shfl-reduced and atomically added to pooled[64] (k_pool eliminated).
// z: 0,1 bg b; 2,3 tg b.
// ---------------------------------------------------------------------------
template<int P>
__global__ __launch_bounds__(256, 8) void k_read(
    const float* __restrict__ attbg,   // [2][64] padded planes
    const float* __restrict__ atttg,   // [2][8]  padded planes
    const float* __restrict__ memRbg, const float* __restrict__ memRtg,
    float* __restrict__ fbg,           // [2 b][CHW] (this scale)
    float* __restrict__ ftg,           // [2 b][CHW] (this scale)
    float* __restrict__ pooled)        // [64]: br*32 + b*16 + c
{
  constexpr int PAD = P / 2, TH = 8 + P - 1, SR = TH + 1;
  __shared__ float at[8 * TH * SR];

  const int tid = threadIdx.x;
  const int x0 = blockIdx.x * 8, y0 = blockIdx.y * 8;
  const int z = blockIdx.z;
  const bool isbg = z < 2;
  const int b = z & 1;
  const int NCH = isbg ? 8 : 1;
  const float* attp = isbg ? (attbg + (size_t)(b * 64) * PL)
                           : (atttg + (size_t)(b * 8) * PL);
  const float* memR = isbg ? memRbg : memRtg;
  float* outp = (isbg ? fbg : ftg) + (size_t)b * CHW;

  const int lane = tid & 63;
  const int wv = tid >> 6;           // c-quad
  const int px = lane & 7, py = lane >> 3;
  const int c0 = wv * 4;

  float acc[4] = {0.f, 0.f, 0.f, 0.f};
  const int oy = y0 + 3 - PAD, ox = x0 + 3 - PAD;

  for (int ch = 0; ch < NCH; ++ch) {
    for (int t = tid; t < 8 * TH * TH; t += 256) {
      int ml = t / (TH * TH);
      int r = t - ml * (TH * TH);
      int ly = r / TH, lx = r - ly * TH;
      at[(ml * TH + ly) * SR + lx] =
          attp[(size_t)(ch * 8 + ml) * PL + (oy + ly) * WP + ox + lx];
    }
    __syncthreads();
    for (int ml = 0; ml < 8; ++ml) {
      const float* atm = at + ml * TH * SR;
      const float* wbase = memR + (size_t)((ch * 8 + ml) * P * P) * C_CH + c0;
#pragma unroll
      for (int u = 0; u < P; ++u) {
#pragma unroll
        for (int v2 = 0; v2 < P; ++v2) {
          float val = atm[(py + u) * SR + (px + v2)];
          const float* wr = wbase + (u * P + v2) * C_CH;
#pragma unroll
          for (int c = 0; c < 4; ++c) acc[c] = fmaf(val, wr[c], acc[c]);
        }
      }
    }
    __syncthreads();
  }

  const int gy = y0 + py, gx = x0 + px;
  int cy = min(P - 1, gy + PAD) - max(0, gy + PAD - (Hdim - 1)) + 1;
  int cx = min(P - 1, gx + PAD) - max(0, gx + PAD - (Wdim - 1)) + 1;
  float inv = 1.f / ((float)(cy * cx) + 1e-8f);
  float psum[4];
#pragma unroll
  for (int c = 0; c < 4; ++c) {
    float v = acc[c] * inv;
    outp[(size_t)(c0 + c) * HWdim + gy * Wdim + gx] = v;
    psum[c] = v;
  }
  // reduce tile sums over the 64 lanes (one wave covers all 64 px)
#pragma unroll
  for (int off = 32; off > 0; off >>= 1) {
#pragma unroll
    for (int c = 0; c < 4; ++c) psum[c] += __shfl_down(psum[c], off, 64);
  }
  if (lane == 0) {
    int base = (isbg ? 0 : 32) + b * 16 + c0;
#pragma unroll
    for (int c = 0; c < 4; ++c)
      gadd(&pooled[base + c], psum[c] * (1.0f / (float)HWdim));
  }
}

// ---------------------------------------------------------------------------
// Fusion MLP + softmax weights
// ---------------------------------------------------------------------------
__global__ __launch_bounds__(128) void k_mlp(
    const float* __restrict__ pooled,
    const float* __restrict__ w1b, const float* __restrict__ b1b,
    const float* __restrict__ w2b, const float* __restrict__ b2b,
    const float* __restrict__ w1t, const float* __restrict__ b1t,
    const float* __restrict__ w2t, const float* __restrict__ b2t,
    float* __restrict__ wt)
{
  __shared__ float hdn[Bdim][4];
  __shared__ float lg[Bdim][48];
  int t = threadIdx.x;
  for (int br = 0; br < 2; ++br) {
    const float* w1 = br ? w1t : w1b;
    const float* b1 = br ? b1t : b1b;
    const float* w2 = br ? w2t : w2b;
    const float* b2 = br ? b2t : b2b;
    if (t < 8) {
      int b = t >> 2, h = t & 3;
      float s = b1[h];
      for (int c = 0; c < C_CH; ++c) s += pooled[br * 32 + b * 16 + c] * w1[h * 16 + c];
      hdn[b][h] = fmaxf(s, 0.f);
    }
    __syncthreads();
    if (t < 96) {
      int b = t / 48, j = t - b * 48;
      float s = b2[j];
      for (int h = 0; h < 4; ++h) s += hdn[b][h] * w2[j * 4 + h];
      lg[b][j] = s;
    }
    __syncthreads();
    if (t < 32) {
      int b = t >> 4, c = t & 15;
      float l0 = lg[b][c], l1 = lg[b][16 + c], l2 = lg[b][32 + c];
      float m = fmaxf(l0, fmaxf(l1, l2));
      float e0 = __expf(l0 - m), e1 = __expf(l1 - m), e2 = __expf(l2 - m);
      float inv = 1.f / (e0 + e1 + e2);
      wt[((br * 2 + b) * 3 + 0) * 16 + c] = e0 * inv;
      wt[((br * 2 + b) * 3 + 1) * 16 + c] = e1 * inv;
      wt[((br * 2 + b) * 3 + 2) * 16 + c] = e2 * inv;
    }
    __syncthreads();
  }
}

__global__ __launch_bounds__(256) void k_out(const float* __restrict__ fbg,
                                             const float* __restrict__ ftg,
                                             const float* __restrict__ wt,
                                             float* __restrict__ out)
{
  int idx = blockIdx.x * 256 + threadIdx.x;      // 0 .. 2*PAIR_ELEMS-1
  int br  = idx >> 19;                           // PAIR_ELEMS == 2^19
  int rem = idx & ((1 << 19) - 1);               // [b][c][HW]
  int b   = rem >> 18;                           // CHW == 2^18
  int off = rem & ((1 << 18) - 1);               // [c][HW]
  int c   = off >> 14;
  const float* f = (br == 0) ? fbg : ftg;
  int wbase = (br * 2 + b) * 3;
  float acc = 0.f;
#pragma unroll
  for (int s = 0; s < 3; ++s) {
    float v = f[(size_t)(s * 2 + b) * CHW + off];
    acc = fmaf(wt[(wbase + s) * 16 + c], v, acc);
  }
  out[idx] = acc;
}

// ---------------------------------------------------------------------------
extern "C" void kernel_launch(void* const* d_in, const int* in_sizes, int n_in,
                              void* d_out, int out_size, void* d_ws, size_t ws_size,
                              hipStream_t stream)
{
  const float* bg = (const float*)d_in[0];
  const float* tg = (const float*)d_in[1];
  const float* bg_mem[3]  = {(const float*)d_in[2],  (const float*)d_in[6],  (const float*)d_in[10]};
  const float* tg_mem[3]  = {(const float*)d_in[3],  (const float*)d_in[7],  (const float*)d_in[11]};
  const float* bg_temp[3] = {(const float*)d_in[4],  (const float*)d_in[8],  (const float*)d_in[12]};
  const float* tg_temp[3] = {(const float*)d_in[5],  (const float*)d_in[9],  (const float*)d_in[13]};
  const float* bg_fc1_w = (const float*)d_in[14];
  const float* bg_fc1_b = (const float*)d_in[15];
  const float* bg_fc2_w = (const float*)d_in[16];
  const float* bg_fc2_b = (const float*)d_in[17];
  const float* tg_fc1_w = (const float*)d_in[18];
  const float* tg_fc1_b = (const float*)d_in[19];
  const float* tg_fc2_w = (const float*)d_in[20];
  const float* tg_fc2_b = (const float*)d_in[21];

  float* ws     = (float*)d_ws;
  float* xpad   = ws;                                  // 64 planes * PL
  float* att    = xpad + (size_t)64 * PL;              // 144 planes * PL
  float* pooled = att + (size_t)144 * PL;              // 64
  float* wt     = pooled + 64;                         // 192
  float* memT   = wt + 192;                            // 95,616
  float* memR   = memT + 95616;                        // 95,616
  float* fbg    = memR + 95616;                        // [3][2][CHW] = 1,572,864
  float* ftg    = fbg + (size_t)6 * CHW;               // [3][2][CHW] = 1,572,864

  float* attbg = att;                                  // [2][64] planes
  float* atttg = att + (size_t)128 * PL;               // [2][8] planes

  // zero xpad + att borders + pooled in one shot
  hipMemsetAsync(xpad, 0, ((size_t)64 * PL + (size_t)144 * PL + 64) * sizeof(float), stream);

  const int   Ms[6] = {64, 64, 64, 8, 8, 8};
  const int   Ps[6] = {3, 5, 7, 3, 5, 7};
  const float* mems[6]  = {bg_mem[0], bg_mem[1], bg_mem[2], tg_mem[0], tg_mem[1], tg_mem[2]};
  const float* temps[6] = {bg_temp[0], bg_temp[1], bg_temp[2], tg_temp[0], tg_temp[1], tg_temp[2]};
  float* memTs[6]; float* memRs[6];
  PrepArgs pa;
  size_t off = 0;
  for (int k = 0; k < 6; ++k) {
    int D = C_CH * Ps[k] * Ps[k];
    memTs[k] = memT + off;
    memRs[k] = memR + off;
    pa.d[k] = {mems[k], temps[k], memTs[k], memRs[k], Ms[k], D, Ps[k]};
    off += (size_t)Ms[k] * D;
  }
  k_prep<<<dim3(196, 6), 256, 0, stream>>>(pa);
  k_padx<<<4096, 256, 0, stream>>>(bg, tg, xpad);

  dim3 gs(16, 16, 4), bs(512);
  dim3 gr(16, 16, 4), brd(256);

  k_sim<3><<<gs, bs, 0, stream>>>(xpad, memTs[0], memTs[3], attbg, atttg);
  k_read<3><<<gr, brd, 0, stream>>>(attbg, atttg, memRs[0], memRs[3],
                                    fbg + (size_t)0 * 2 * CHW, ftg + (size_t)0 * 2 * CHW, pooled);
  k_sim<5><<<gs, bs, 0, stream>>>(xpad, memTs[1], memTs[4], attbg, atttg);
  k_read<5><<<gr, brd, 0, stream>>>(attbg, atttg, memRs[1], memRs[4],
                                    fbg + (size_t)1 * 2 * CHW, ftg + (size_t)1 * 2 * CHW, pooled);
  k_sim<7><<<gs, bs, 0, stream>>>(xpad, memTs[2], memTs[5], attbg, atttg);
  k_read<7><<<gr, brd, 0, stream>>>(attbg, atttg, memRs[2], memRs[5],
                                    fbg + (size_t)2 * 2 * CHW, ftg + (size_t)2 * 2 * CHW, pooled);

  k_mlp<<<1, 128, 0, stream>>>(pooled, bg_fc1_w, bg_fc1_b, bg_fc2_w, bg_fc2_b,
                               tg_fc1_w, tg_fc1_b, tg_fc2_w, tg_fc2_b, wt);
  k_out<<<(2 * PAIR_ELEMS) / 256, 256, 0, stream>>>(fbg, ftg, wt, (float*)d_out);
}

// Round 7
// 340.694 us; speedup vs baseline: 3.1627x; 3.1627x over previous
//
#include <hip/hip_runtime.h>

#define C_CH 16
#define Hdim 128
#define Wdim 128
#define HWdim 16384
#define CHW (C_CH * HWdim)                 // 262144 floats: one [C][H][W] slab
#define Bdim 2
#define PAIR_ELEMS (Bdim * CHW)            // 524288

// padded canvas geometry (border 3 = max P/2, zeroed once per launch)
#define HP 134
#define WP 136
#define PL (HP * WP)                       // 18224 floats per plane

typedef float v2f __attribute__((ext_vector_type(2)));

__device__ __forceinline__ void gadd(float* p, float v) {
  __hip_atomic_fetch_add(p, v, __ATOMIC_RELAXED, __HIP_MEMORY_SCOPE_AGENT);
}

// ---------------------------------------------------------------------------
// Prep: memT[d][m] = mem * temp/sqrt(D)   (sim conv weights, m-contiguous)
//       memR[m][u][v][c]                  (kernel-flipped, c-contiguous)
// ---------------------------------------------------------------------------
struct PrepDesc {
  const float* mem;
  const float* temp;
  float* memT;
  float* memR;
  int M, D, P;
};
struct PrepArgs { PrepDesc d[6]; };

__global__ __launch_bounds__(256) void k_prep(PrepArgs a) {
  PrepDesc de = a.d[blockIdx.y];
  int n = de.M * de.D;
  int idx = blockIdx.x * 256 + threadIdx.x;
  if (idx >= n) return;
  int m = idx / de.D;
  int d = idx - m * de.D;
  float v = de.mem[idx];
  float sc = de.temp[0] / sqrtf((float)de.D);
  de.memT[d * de.M + m] = v * sc;
  int pp = de.P * de.P;
  int c = d / pp;
  int r = d - c * pp;
  int i = r / de.P;
  int j = r - i * de.P;
  de.memR[((m * de.P + (de.P - 1 - i)) * de.P + (de.P - 1 - j)) * C_CH + c] = v;
}

// ---------------------------------------------------------------------------
// Copy inputs into padded canvas: xpad plane order [bg b0, bg b1, tg b0, tg b1]
// ---------------------------------------------------------------------------
__global__ __launch_bounds__(256) void k_padx(const float* __restrict__ bg,
                                              const float* __restrict__ tg,
                                              float* __restrict__ xpad)
{
  int idx = blockIdx.x * 256 + threadIdx.x;     // 64 planes * HW
  int p = idx >> 14;                            // plane 0..63
  int hw = idx & (HWdim - 1);
  int y = hw >> 7, x = hw & 127;
  int z = p >> 4, c = p & 15;
  const float* src = (z < 2) ? bg : tg;
  int b = z & 1;
  float v = src[((b * C_CH + c) << 14) + hw];
  xpad[(size_t)p * PL + (y + 3) * WP + (x + 3)] = v;
}

// ---------------------------------------------------------------------------
// Sim conv + per-pixel softmax -> att (padded layout). One dispatch per scale.
// 8x8 tile, 512 thr, 8 waves split M. z: {bg b0, bg b1, tg b0, tg b1}.
// bg inner loop uses float2 packed FMA (v_pk_fma_f32).
// ---------------------------------------------------------------------------
template<int P>
__device__ __forceinline__ void sim_core_bg(
    const float* __restrict__ xt, float* __restrict__ red,
    const float* __restrict__ memT, float* __restrict__ att,
    int wv, int lane, int x0, int y0)
{
  constexpr int TH = 8 + P - 1, SR = TH + 1;
  constexpr int M = 64, MC = 8;
  const int px = lane & 7, py = lane >> 3;
  const int m0 = wv * MC;
  v2f acc2[4];
#pragma unroll
  for (int mm = 0; mm < 4; ++mm) acc2[mm] = (v2f){0.f, 0.f};

  for (int c = 0; c < C_CH; ++c) {
#pragma unroll
    for (int i = 0; i < P; ++i) {
#pragma unroll
      for (int j = 0; j < P; ++j) {
        float val = xt[(c * TH + py + i) * SR + (px + j)];
        const v2f* wr = (const v2f*)(memT + (size_t)(((c * P + i) * P + j)) * M + m0);
        v2f vv = {val, val};
#pragma unroll
        for (int mm = 0; mm < 4; ++mm)
          acc2[mm] = __builtin_elementwise_fma(vv, wr[mm], acc2[mm]);
      }
    }
  }

  float acc[MC];
#pragma unroll
  for (int mm = 0; mm < 4; ++mm) { acc[2 * mm] = acc2[mm].x; acc[2 * mm + 1] = acc2[mm].y; }

  float pm = acc[0];
#pragma unroll
  for (int mm = 1; mm < MC; ++mm) pm = fmaxf(pm, acc[mm]);
  red[wv * 64 + lane] = pm;
  __syncthreads();
  float gm = red[lane];
#pragma unroll
  for (int w = 1; w < 8; ++w) gm = fmaxf(gm, red[w * 64 + lane]);
  __syncthreads();
  float ps = 0.f;
#pragma unroll
  for (int mm = 0; mm < MC; ++mm) { acc[mm] = __expf(acc[mm] - gm); ps += acc[mm]; }
  red[wv * 64 + lane] = ps;
  __syncthreads();
  float tot = 0.f;
#pragma unroll
  for (int w = 0; w < 8; ++w) tot += red[w * 64 + lane];
  float inv = 1.f / tot;

  const int gy = y0 + py, gx = x0 + px;
#pragma unroll
  for (int mm = 0; mm < MC; ++mm)
    att[(size_t)(m0 + mm) * PL + (gy + 3) * WP + (gx + 3)] = acc[mm] * inv;
}

template<int P>
__device__ __forceinline__ void sim_core_tg(
    const float* __restrict__ xt, float* __restrict__ red,
    const float* __restrict__ memT, float* __restrict__ att,
    int wv, int lane, int x0, int y0)
{
  constexpr int TH = 8 + P - 1, SR = TH + 1;
  constexpr int M = 8;
  const int px = lane & 7, py = lane >> 3;
  const int m0 = wv;           // 8 waves, 1 memory each
  float acc = 0.f;

  for (int c = 0; c < C_CH; ++c) {
#pragma unroll
    for (int i = 0; i < P; ++i) {
#pragma unroll
      for (int j = 0; j < P; ++j) {
        float val = xt[(c * TH + py + i) * SR + (px + j)];
        acc = fmaf(val, memT[(size_t)(((c * P + i) * P + j)) * M + m0], acc);
      }
    }
  }

  red[wv * 64 + lane] = acc;
  __syncthreads();
  float gm = red[lane];
#pragma unroll
  for (int w = 1; w < 8; ++w) gm = fmaxf(gm, red[w * 64 + lane]);
  __syncthreads();
  float e = __expf(acc - gm);
  red[wv * 64 + lane] = e;
  __syncthreads();
  float tot = 0.f;
#pragma unroll
  for (int w = 0; w < 8; ++w) tot += red[w * 64 + lane];

  const int gy = y0 + py, gx = x0 + px;
  att[(size_t)m0 * PL + (gy + 3) * WP + (gx + 3)] = e / tot;
}

template<int P>
__global__ __launch_bounds__(512, 8) void k_sim(
    const float* __restrict__ xpad,
    const float* __restrict__ memTbg, const float* __restrict__ memTtg,
    float* __restrict__ attbg,   // [2][64] padded planes
    float* __restrict__ atttg)   // [2][8]  padded planes
{
  constexpr int PAD = P / 2, TH = 8 + P - 1, SR = TH + 1;
  __shared__ float xt[C_CH * TH * SR];
  __shared__ float red[8 * 64];

  const int tid = threadIdx.x;
  const int wv = __builtin_amdgcn_readfirstlane(tid >> 6);
  const int lane = tid & 63;
  const int x0 = blockIdx.x * 8, y0 = blockIdx.y * 8;
  const int z = blockIdx.z;
  const bool isbg = z < 2;
  const int b = z & 1;

  const float* xp = xpad + (size_t)(z * 16) * PL;
  const int oy = y0 + 3 - PAD, ox = x0 + 3 - PAD;
  for (int t = tid; t < C_CH * TH * TH; t += 512) {
    int c = t / (TH * TH);
    int r = t - c * (TH * TH);
    int ly = r / TH, lx = r - ly * TH;
    xt[(c * TH + ly) * SR + lx] = xp[(size_t)c * PL + (oy + ly) * WP + ox + lx];
  }
  __syncthreads();

  if (isbg) sim_core_bg<P>(xt, red, memTbg, attbg + (size_t)(b * 64) * PL, wv, lane, x0, y0);
  else      sim_core_tg<P>(xt, red, memTtg, atttg + (size_t)(b * 8) * PL, wv, lane, x0, y0);
}

// ---------------------------------------------------------------------------
// Read conv (R5 structure): 16x16 pixel tile, 1 thread = 1 output pixel,
// 16-c register accumulator (float2-packed), 8 planes staged ONCE per block.
// bg: 8 chunks -> partial slabs pbg[chunk][b]; tg: final.
// z: 0..15 -> bg (chunk=z>>1, b=z&1); 16..17 -> tg (b=z-16).
// ---------------------------------------------------------------------------
template<int P>
__global__ __launch_bounds__(256, 8) void k_read(
    const float* __restrict__ attbg,   // [2][64] padded planes
    const float* __restrict__ atttg,   // [2][8]  padded planes
    const float* __restrict__ memRbg, const float* __restrict__ memRtg,
    float* __restrict__ pbg,           // [8 chunk][2 b][CHW] (this scale)
    float* __restrict__ ftg)           // [2 b][CHW]          (this scale)
{
  constexpr int PAD = P / 2, TH = 16 + P - 1, SR = TH + 1;
  __shared__ float at[8 * TH * SR];

  const int tid = threadIdx.x;
  const int x0 = blockIdx.x * 16, y0 = blockIdx.y * 16;
  const int z = blockIdx.z;
  const bool isbg = z < 16;
  const int b = isbg ? (z & 1) : (z - 16);
  const int chunk = isbg ? (z >> 1) : 0;
  const int mbase = chunk * 8;
  const float* attp = isbg ? (attbg + (size_t)(b * 64 + mbase) * PL)
                           : (atttg + (size_t)(b * 8) * PL);
  const float* memR = isbg ? memRbg : memRtg;
  float* outp = isbg ? (pbg + (size_t)(chunk * 2 + b) * CHW)
                     : (ftg + (size_t)b * CHW);

  // branch-free staging of 8 att planes (+halo) from padded canvas
  const int oy = y0 + 3 - PAD, ox = x0 + 3 - PAD;
  for (int t = tid; t < 8 * TH * TH; t += 256) {
    int ml = t / (TH * TH);
    int r = t - ml * (TH * TH);
    int ly = r / TH, lx = r - ly * TH;
    at[(ml * TH + ly) * SR + lx] = attp[(size_t)ml * PL + (oy + ly) * WP + ox + lx];
  }
  __syncthreads();

  const int px = tid & 15, py = tid >> 4;
  v2f acc2[8];
#pragma unroll
  for (int c = 0; c < 8; ++c) acc2[c] = (v2f){0.f, 0.f};

  for (int ml = 0; ml < 8; ++ml) {
    const float* atm = at + ml * TH * SR;
    const v2f* wbase = (const v2f*)(memR + (size_t)((mbase + ml) * P * P) * C_CH);
#pragma unroll
    for (int u = 0; u < P; ++u) {
#pragma unroll
      for (int v2_ = 0; v2_ < P; ++v2_) {
        float val = atm[(py + u) * SR + (px + v2_)];
        const v2f* wr = wbase + (u * P + v2_) * 8;
        v2f vv = {val, val};
#pragma unroll
        for (int c = 0; c < 8; ++c)
          acc2[c] = __builtin_elementwise_fma(vv, wr[c], acc2[c]);
      }
    }
  }

  const int gy = y0 + py, gx = x0 + px;
  int cy = min(P - 1, gy + PAD) - max(0, gy + PAD - (Hdim - 1)) + 1;
  int cx = min(P - 1, gx + PAD) - max(0, gx + PAD - (Wdim - 1)) + 1;
  float inv = 1.f / ((float)(cy * cx) + 1e-8f);
#pragma unroll
  for (int c = 0; c < 8; ++c) {
    outp[(size_t)(2 * c) * HWdim + gy * Wdim + gx]     = acc2[c].x * inv;
    outp[(size_t)(2 * c + 1) * HWdim + gy * Wdim + gx] = acc2[c].y * inv;
  }
}

// ---------------------------------------------------------------------------
// Sum partial slabs -> final fbg; fused pooled-mean reduction (bg + tg).
// Grid 768 blocks: bid<384 bg (sum 8 partials, write final, pool);
// bid>=384 tg (read final ftg, pool only). Block = (s,b,c,q) strip of 4096.
// ---------------------------------------------------------------------------
__global__ __launch_bounds__(256) void k_sum(const float* __restrict__ pbg,
                                             const float* __restrict__ ftg,
                                             float* __restrict__ fbg,
                                             float* __restrict__ pooled)
{
  __shared__ float red[256];
  int bid = blockIdx.x;
  bool isbg = bid < 384;
  int r = isbg ? bid : bid - 384;
  int s = r >> 7;
  int rr = r & 127;
  int b = rr >> 6;
  int c = (rr >> 2) & 15;
  int q = rr & 3;
  size_t base = (size_t)c * HWdim + q * 4096;
  float lsum = 0.f;
  if (isbg) {
    const float* p0 = pbg + ((size_t)(s * 8) * 2 + b) * CHW + base;
    float* fo = fbg + (size_t)(s * 2 + b) * CHW + base;
    for (int t = threadIdx.x; t < 4096; t += 256) {
      float v = 0.f;
#pragma unroll
      for (int ch = 0; ch < 8; ++ch) v += p0[(size_t)ch * 2 * CHW + t];
      fo[t] = v;
      lsum += v;
    }
  } else {
    const float* f0 = ftg + (size_t)(s * 2 + b) * CHW + base;
    for (int t = threadIdx.x; t < 4096; t += 256) lsum += f0[t];
  }
  red[threadIdx.x] = lsum;
  __syncthreads();
  for (int off = 128; off > 0; off >>= 1) {
    if ((int)threadIdx.x < off) red[threadIdx.x] += red[threadIdx.x + off];
    __syncthreads();
  }
  if (threadIdx.x == 0)
    gadd(&pooled[(isbg ? 0 : 32) + b * 16 + c], red[0] * (1.0f / (float)HWdim));
}

// ---------------------------------------------------------------------------
// Fusion MLP + softmax weights
// ---------------------------------------------------------------------------
__global__ __launch_bounds__(128) void k_mlp(
    const float* __restrict__ pooled,
    const float* __restrict__ w1b, const float* __restrict__ b1b,
    const float* __restrict__ w2b, const float* __restrict__ b2b,
    const float* __restrict__ w1t, const float* __restrict__ b1t,
    const float* __restrict__ w2t, const float* __restrict__ b2t,
    float* __restrict__ wt)
{
  __shared__ float hdn[Bdim][4];
  __shared__ float lg[Bdim][48];
  int t = threadIdx.x;
  for (int br = 0; br < 2; ++br) {
    const float* w1 = br ? w1t : w1b;
    const float* b1 = br ? b1t : b1b;
    const float* w2 = br ? w2t : w2b;
    const float* b2 = br ? b2t : b2b;
    if (t < 8) {
      int b = t >> 2, h = t & 3;
      float s = b1[h];
      for (int c = 0; c < C_CH; ++c) s += pooled[br * 32 + b * 16 + c] * w1[h * 16 + c];
      hdn[b][h] = fmaxf(s, 0.f);
    }
    __syncthreads();
    if (t < 96) {
      int b = t / 48, j = t - b * 48;
      float s = b2[j];
      for (int h = 0; h < 4; ++h) s += hdn[b][h] * w2[j * 4 + h];
      lg[b][j] = s;
    }
    __syncthreads();
    if (t < 32) {
      int b = t >> 4, c = t & 15;
      float l0 = lg[b][c], l1 = lg[b][16 + c], l2 = lg[b][32 + c];
      float m = fmaxf(l0, fmaxf(l1, l2));
      float e0 = __expf(l0 - m), e1 = __expf(l1 - m), e2 = __expf(l2 - m);
      float inv = 1.f / (e0 + e1 + e2);
      wt[((br * 2 + b) * 3 + 0) * 16 + c] = e0 * inv;
      wt[((br * 2 + b) * 3 + 1) * 16 + c] = e1 * inv;
      wt[((br * 2 + b) * 3 + 2) * 16 + c] = e2 * inv;
    }
    __syncthreads();
  }
}

__global__ __launch_bounds__(256) void k_out(const float* __restrict__ fbg,
                                             const float* __restrict__ ftg,
                                             const float* __restrict__ wt,
                                             float* __restrict__ out)
{
  int idx = blockIdx.x * 256 + threadIdx.x;      // 0 .. 2*PAIR_ELEMS-1
  int br  = idx >> 19;                           // PAIR_ELEMS == 2^19
  int rem = idx & ((1 << 19) - 1);               // [b][c][HW]
  int b   = rem >> 18;                           // CHW == 2^18
  int off = rem & ((1 << 18) - 1);               // [c][HW]
  int c   = off >> 14;
  const float* f = (br == 0) ? fbg : ftg;
  int wbase = (br * 2 + b) * 3;
  float acc = 0.f;
#pragma unroll
  for (int s = 0; s < 3; ++s) {
    float v = f[(size_t)(s * 2 + b) * CHW + off];
    acc = fmaf(wt[(wbase + s) * 16 + c], v, acc);
  }
  out[idx] = acc;
}

// ---------------------------------------------------------------------------
extern "C" void kernel_launch(void* const* d_in, const int* in_sizes, int n_in,
                              void* d_out, int out_size, void* d_ws, size_t ws_size,
                              hipStream_t stream)
{
  const float* bg = (const float*)d_in[0];
  const float* tg = (const float*)d_in[1];
  const float* bg_mem[3]  = {(const float*)d_in[2],  (const float*)d_in[6],  (const float*)d_in[10]};
  const float* tg_mem[3]  = {(const float*)d_in[3],  (const float*)d_in[7],  (const float*)d_in[11]};
  const float* bg_temp[3] = {(const float*)d_in[4],  (const float*)d_in[8],  (const float*)d_in[12]};
  const float* tg_temp[3] = {(const float*)d_in[5],  (const float*)d_in[9],  (const float*)d_in[13]};
  const float* bg_fc1_w = (const float*)d_in[14];
  const float* bg_fc1_b = (const float*)d_in[15];
  const float* bg_fc2_w = (const float*)d_in[16];
  const float* bg_fc2_b = (const float*)d_in[17];
  const float* tg_fc1_w = (const float*)d_in[18];
  const float* tg_fc1_b = (const float*)d_in[19];
  const float* tg_fc2_w = (const float*)d_in[20];
  const float* tg_fc2_b = (const float*)d_in[21];

  float* ws     = (float*)d_ws;
  float* xpad   = ws;                                  // 64 planes * PL
  float* att    = xpad + (size_t)64 * PL;              // 144 planes * PL
  float* pooled = att + (size_t)144 * PL;              // 64
  float* wt     = pooled + 64;                         // 192
  float* memT   = wt + 192;                            // 95,616
  float* memR   = memT + 95616;                        // 95,616
  float* pbg    = memR + 95616;                        // [3][8][2][CHW] = 12.6M floats
  float* ftg    = pbg + (size_t)48 * CHW;              // [3][2][CHW]
  float* fbg    = ftg + (size_t)6 * CHW;               // [3][2][CHW]

  float* attbg = att;                                  // [2][64] planes
  float* atttg = att + (size_t)128 * PL;               // [2][8] planes

  // zero xpad + att (borders) + pooled (atomic target) in one shot
  hipMemsetAsync(xpad, 0, ((size_t)64 * PL + (size_t)144 * PL + 64) * sizeof(float), stream);

  const int   Ms[6] = {64, 64, 64, 8, 8, 8};
  const int   Ps[6] = {3, 5, 7, 3, 5, 7};
  const float* mems[6]  = {bg_mem[0], bg_mem[1], bg_mem[2], tg_mem[0], tg_mem[1], tg_mem[2]};
  const float* temps[6] = {bg_temp[0], bg_temp[1], bg_temp[2], tg_temp[0], tg_temp[1], tg_temp[2]};
  float* memTs[6]; float* memRs[6];
  PrepArgs pa;
  size_t off = 0;
  for (int k = 0; k < 6; ++k) {
    int D = C_CH * Ps[k] * Ps[k];
    memTs[k] = memT + off;
    memRs[k] = memR + off;
    pa.d[k] = {mems[k], temps[k], memTs[k], memRs[k], Ms[k], D, Ps[k]};
    off += (size_t)Ms[k] * D;
  }
  k_prep<<<dim3(196, 6), 256, 0, stream>>>(pa);
  k_padx<<<4096, 256, 0, stream>>>(bg, tg, xpad);

  dim3 gs(16, 16, 4), bs(512);
  dim3 gr(8, 8, 18), brd(256);

  k_sim<3><<<gs, bs, 0, stream>>>(xpad, memTs[0], memTs[3], attbg, atttg);
  k_read<3><<<gr, brd, 0, stream>>>(attbg, atttg, memRs[0], memRs[3],
                                    pbg + (size_t)0 * 16 * CHW, ftg + (size_t)0 * 2 * CHW);
  k_sim<5><<<gs, bs, 0, stream>>>(xpad, memTs[1], memTs[4], attbg, atttg);
  k_read<5><<<gr, brd, 0, stream>>>(attbg, atttg, memRs[1], memRs[4],
                                    pbg + (size_t)1 * 16 * CHW, ftg + (size_t)1 * 2 * CHW);
  k_sim<7><<<gs, bs, 0, stream>>>(xpad, memTs[2], memTs[5], attbg, atttg);
  k_read<7><<<gr, brd, 0, stream>>>(attbg, atttg, memRs[2], memRs[5],
                                    pbg + (size_t)2 * 16 * CHW, ftg + (size_t)2 * 2 * CHW);

  k_sum<<<768, 256, 0, stream>>>(pbg, ftg, fbg, pooled);
  k_mlp<<<1, 128, 0, stream>>>(pooled, bg_fc1_w, bg_fc1_b, bg_fc2_w, bg_fc2_b,
                               tg_fc1_w, tg_fc1_b, tg_fc2_w, tg_fc2_b, wt);
  k_out<<<(2 * PAIR_ELEMS) / 256, 256, 0, stream>>>(fbg, ftg, wt, (float*)d_out);
}